// Round 10
// baseline (2985.648 us; speedup 1.0000x reference)
//
#include <hip/hip_runtime.h>
#include <cmath>

#define NB   32
#define TE   128
#define TD   32
#define VOC  32000
#define EMB  256
#define HH   512
#define CTXD 1024
#define DCW  1536   // dcat row: [ctx 1024 | h 512]

// ws float offsets. ints 0..2047: barrier regions, 16 groups x 128 ints
// (8 lines x 16 ints each): scan groups 0-7 @0, dec groups 0-7 @1024.
#define OHS  2048                        // harr [2][129][NB][HH]
#define OEO  (OHS + 2*129*NB*HH)         // enc_out [NB][TE][CTXD]
#define OEP  (OEO + NB*TE*CTXD)          // epre [NB][TE][8]
#define ODC  (OEP + NB*TE*8)             // dcat [TD+1][NB][DCW]
#define WSEND (ODC + (TD+1)*NB*DCW)      // ~40.3MB

__device__ __forceinline__ float sigf(float x) { return 1.0f / (1.0f + expf(-x)); }
__device__ __forceinline__ float hsum4(float4 v) { return (v.x + v.y) + (v.z + v.w); }

__device__ __forceinline__ void stg1(float* p, float v) {
  __hip_atomic_store(p, v, __ATOMIC_RELAXED, __HIP_MEMORY_SCOPE_AGENT);
}

__device__ __forceinline__ void fma4(float4& a, const float4 w, const float4 u) {
  a.x = fmaf(w.x, u.x, a.x); a.y = fmaf(w.y, u.y, a.y);
  a.z = fmaf(w.z, u.z, a.z); a.w = fmaf(w.w, u.w, a.w);
}

// Split-phase group barrier (32 participants, arrivals over 8 lines).
// All-relaxed (agent-acquire = buffer_inv sc1 = L2 nuke, R2 regression).
// gbarArrive's __syncthreads drains vmcnt (sc1 stores at L3) before the flag;
// cross-block data is read at per-step-fresh addresses only. Between arrive
// and wait the caller may do independent "shadow" work (hidden under latency).
__device__ __forceinline__ void gbarArrive(int* bar, int idx) {
  __syncthreads();
  if (threadIdx.x == 0) {
    __hip_atomic_fetch_add(bar + (idx & 7) * 16, 1,
                           __ATOMIC_RELAXED, __HIP_MEMORY_SCOPE_AGENT);
  }
}
__device__ __forceinline__ void gbarWait(int* bar, int target) {
  if (threadIdx.x < 64) {
    const int ln = threadIdx.x;
    int it = 0;
    while (true) {   // busy spin: iteration self-throttles on L3 RTT
      int v = (ln < 8)
        ? __hip_atomic_load(bar + ln * 16, __ATOMIC_RELAXED, __HIP_MEMORY_SCOPE_AGENT)
        : 0;
      v += __shfl_xor(v, 1); v += __shfl_xor(v, 2); v += __shfl_xor(v, 4);
      v = __shfl(v, 0);
      if (v >= target) break;
      if (++it > (1 << 21)) break;  // safety bail: garbage beats hang
    }
  }
  __syncthreads();
}

// ---------------- BiLSTM scan: 256 blocks x 512 thr, persistent ----------------
// group g = bid&7 -> (dir = g>>2, bg = g&3: 8 batches); cg = bid>>3: 16 h-cols
// (64 gate rows r = gate*16+col). Waves: (ks = w&3, rh = w>>2); lane = rq*16+kl.
// Chunk map per ks: 1 x-chunk (c=ks, SHADOW: computed pre-wait, token-only) +
// 2 h-chunks (c = 4+2ks, 5+2ks, ON-PATH). Wreg[8][3] = 96 VGPR, loaded once.
__global__ void __launch_bounds__(512)
scan_kernel(const int* __restrict__ enc_in, const int* __restrict__ lens,
            const float* __restrict__ emb_src,
            const float* __restrict__ Wih_f, const float* __restrict__ Whh_f,
            const float* __restrict__ bih_f, const float* __restrict__ bhh_f,
            const float* __restrict__ Wih_b, const float* __restrict__ Whh_b,
            const float* __restrict__ bih_b, const float* __restrict__ bhh_b,
            float* __restrict__ ws)
{
  const int tid = threadIdx.x, bid = blockIdx.x;
  const int g = bid & 7, cg = bid >> 3;
  const int dir = g >> 2, bg = g & 3;
  int* bar = (int*)ws + g * 128;
  float* harr = ws + OHS;
  float* eo   = ws + OEO;

  asm volatile("buffer_inv sc1" ::: "memory");  // purge stale clean lines (graph replays)

  __shared__ int   tokL[TE][8];        // this bg's 8 batches
  __shared__ float lds_p[8][4][68];    // [bb][ks][row(64)+pad]; shadow '=', on-path '+='

  for (int i = tid; i < TE * 8; i += 512) {
    int bb = i & 7, s = i >> 3;
    int b = bg * 8 + bb;
    int t = s;
    if (dir) { int L = lens[b]; t = (s < L) ? (L - 1 - s) : s; }
    tokL[s][bb] = enc_in[b * TE + t];
  }
  if (tid < 128) {   // zero own h0 slice: 8 b x 16 cols
    int bb = tid >> 4, col = tid & 15;
    stg1(&harr[((size_t)(dir * 129) * NB + bg * 8 + bb) * HH + cg * 16 + col], 0.0f);
  }

  const int lane = tid & 63, w = tid >> 6;
  const int ks = w & 3, rh = w >> 2;
  const int rq = lane >> 4, kl = lane & 15;
  const int j0 = cg * 16;
  const float* Wih = dir ? Wih_b : Wih_f;
  const float* Whh = dir ? Whh_b : Whh_f;

  // weights once: rows r = rh*32 + rq*8 + ri (r = gate*16+col)
  float4 Wreg[8][3];
  #pragma unroll
  for (int ri = 0; ri < 8; ++ri) {
    int r = rh * 32 + rq * 8 + ri;
    int o = (r >> 4) * HH + j0 + (r & 15);
    Wreg[ri][0] = *((const float4*)Wih + (size_t)o * 64 + ks * 16 + kl);
    Wreg[ri][1] = *((const float4*)Whh + (size_t)o * 128 + (2 * ks) * 16 + kl);
    Wreg[ri][2] = *((const float4*)Whh + (size_t)o * 128 + (2 * ks + 1) * 16 + kl);
  }

  // updater role (tid<128): (b_u, col_u); c-state in register
  const int b_u = tid >> 4, col_u = tid & 15;
  const int j_u = j0 + col_u;
  const int bglob = bg * 8 + b_u;
  const int Lu = (tid < 128) ? lens[bglob] : 0;
  float bs0 = 0, bs1 = 0, bs2 = 0, bs3 = 0;
  if (tid < 128) {
    const float* bih = dir ? bih_b : bih_f;
    const float* bhh = dir ? bhh_b : bhh_f;
    bs0 = bih[j_u] + bhh[j_u];
    bs1 = bih[HH + j_u] + bhh[HH + j_u];
    bs2 = bih[2 * HH + j_u] + bhh[2 * HH + j_u];
    bs3 = bih[3 * HH + j_u] + bhh[3 * HH + j_u];
  }
  float cst = 0.0f;

  // shadow: x-partials for step s into lds_p (token-only; pre-wait safe)
  auto SHADOW = [&](int s) {
    #pragma unroll 2
    for (int bb = 0; bb < 8; ++bb) {
      const int tok = tokL[s][bb];
      float4 ux = *((const float4*)emb_src + (size_t)tok * 64 + ks * 16 + kl);
      float sx[8];
      #pragma unroll
      for (int ri = 0; ri < 8; ++ri) {
        float4 a = {0, 0, 0, 0};
        fma4(a, Wreg[ri][0], ux);
        sx[ri] = hsum4(a);
      }
      #pragma unroll
      for (int ri = 0; ri < 8; ++ri) {
        sx[ri] += __shfl_xor(sx[ri], 1);
        sx[ri] += __shfl_xor(sx[ri], 2);
        sx[ri] += __shfl_xor(sx[ri], 4);
        sx[ri] += __shfl_xor(sx[ri], 8);
      }
      if (kl == 0) {
        int r0 = rh * 32 + rq * 8;
        float4 lo = {sx[0], sx[1], sx[2], sx[3]};
        float4 hi = {sx[4], sx[5], sx[6], sx[7]};
        *(float4*)&lds_p[bb][ks][r0]     = lo;
        *(float4*)&lds_p[bb][ks][r0 + 4] = hi;
      }
    }
  };

  gbarArrive(bar, cg);
  SHADOW(0);
  gbarWait(bar, 32);
  int tgt = 64;

  for (int s = 0; s < TE; ++s) {
    // ---- on-path: h-dots (2 chunks), preload all u first ----
    {
      const float4* h4 = (const float4*)(harr + ((size_t)(dir * 129 + s) * NB) * HH);
      float4 uu[8][2];
      #pragma unroll
      for (int bb = 0; bb < 8; ++bb) {
        const int b = bg * 8 + bb;
        uu[bb][0] = h4[(size_t)b * 128 + (2 * ks) * 16 + kl];
        uu[bb][1] = h4[(size_t)b * 128 + (2 * ks + 1) * 16 + kl];
      }
      #pragma unroll
      for (int bb = 0; bb < 8; ++bb) {
        float sc[8];
        #pragma unroll
        for (int ri = 0; ri < 8; ++ri) {
          float4 a = {0, 0, 0, 0};
          fma4(a, Wreg[ri][1], uu[bb][0]);
          fma4(a, Wreg[ri][2], uu[bb][1]);
          sc[ri] = hsum4(a);
        }
        #pragma unroll
        for (int ri = 0; ri < 8; ++ri) {
          sc[ri] += __shfl_xor(sc[ri], 1);
          sc[ri] += __shfl_xor(sc[ri], 2);
          sc[ri] += __shfl_xor(sc[ri], 4);
          sc[ri] += __shfl_xor(sc[ri], 8);
        }
        if (kl == 0) {
          int r0 = rh * 32 + rq * 8;
          float4 lo = *(float4*)&lds_p[bb][ks][r0];
          float4 hi = *(float4*)&lds_p[bb][ks][r0 + 4];
          lo.x += sc[0]; lo.y += sc[1]; lo.z += sc[2]; lo.w += sc[3];
          hi.x += sc[4]; hi.y += sc[5]; hi.z += sc[6]; hi.w += sc[7];
          *(float4*)&lds_p[bb][ks][r0]     = lo;
          *(float4*)&lds_p[bb][ks][r0 + 4] = hi;
        }
      }
    }
    __syncthreads();

    if (tid < 128) {
      float gi = bs0, gf = bs1, gg = bs2, go = bs3;
      #pragma unroll
      for (int k2 = 0; k2 < 4; ++k2) {
        gi += lds_p[b_u][k2][col_u];
        gf += lds_p[b_u][k2][16 + col_u];
        gg += lds_p[b_u][k2][32 + col_u];
        go += lds_p[b_u][k2][48 + col_u];
      }
      float c = sigf(gf) * cst + sigf(gi) * tanhf(gg);
      cst = c;
      float h = sigf(go) * tanhf(c);
      stg1(&harr[((size_t)(dir * 129 + s + 1) * NB + bglob) * HH + j_u], h);
      float hm = (s < Lu) ? h : 0.0f;
      int pos = dir ? ((s < Lu) ? (Lu - 1 - s) : s) : s;
      eo[((size_t)bglob * TE + pos) * CTXD + dir * HH + j_u] = hm;  // plain store
    }
    gbarArrive(bar, cg);
    if (s + 1 < TE) SHADOW(s + 1);
    gbarWait(bar, tgt); tgt += 32;
  }
}

// ---------------- Decoder: 256 blocks x 512 thr, persistent ----------------
// group g = bid&7: 4 batches; cg = bid>>3: 16 GRU cols + 32-d ctx slice.
// Chunk map per ks: 1 x + 2 h chunks SHADOW (after arrive1; h_s known),
// 4 ctx chunks ON-PATH (after wait1). WD[6][7]=168 VGPR register weights.
__global__ void __launch_bounds__(512)
dec_kernel(const int* __restrict__ dec_in, const int* __restrict__ lens,
           const float* __restrict__ emb_tgt,
           const float* __restrict__ gWih, const float* __restrict__ gWhh,
           const float* __restrict__ gbih, const float* __restrict__ gbhh,
           const float* __restrict__ attn_W, const float* __restrict__ attn_b,
           const float* __restrict__ attn_v,
           float* __restrict__ ws)
{
  const int tid = threadIdx.x, bid = blockIdx.x;
  const int g = bid & 7, cg = bid >> 3;
  int* bar = (int*)ws + 1024 + g * 128;
  float* eo   = ws + OEO;
  float* ep   = ws + OEP;
  float* dcat = ws + ODC;

  asm volatile("buffer_inv sc1" ::: "memory");

  __shared__ int   tokD[TD][4];
  __shared__ int   lensh[4];
  __shared__ float av8v[8];
  __shared__ float hpv[4][8];
  __shared__ float elds[4][128];
  __shared__ float wlds[4][128];
  __shared__ float mxs[4], invs[4];
  __shared__ float cpart[4][4][32];
  __shared__ float lds_pd[2][4][4][52];   // [i/h][bb][ks][r]; shadow '=', on-path '+='

  for (int i = tid; i < TD * 4; i += 512) {
    int bb = i & 3, s = i >> 2;
    tokD[s][bb] = dec_in[(g * 4 + bb) * TD + s];
  }
  if (tid < 8) av8v[tid] = attn_v[tid];
  if (tid < 4) lensh[tid] = lens[g * 4 + tid];

  // group-local pre-phase: ep for own 4 batches + h0
  {
    const int idx = cg * 512 + tid;
    if (idx < 4 * TE * 8) {
      int a = idx & 7, t = (idx >> 3) & 127, bb = idx >> 10;
      int b = g * 4 + bb;
      float acc = attn_b[a];
      const float* er = &eo[((size_t)b * TE + t) * CTXD];
      for (int d = 0; d < CTXD; d += 4) {
        float4 ev = *(const float4*)&er[d];
        acc = fmaf(ev.x, attn_W[(d + 0) * 8 + a], acc);
        acc = fmaf(ev.y, attn_W[(d + 1) * 8 + a], acc);
        acc = fmaf(ev.z, attn_W[(d + 2) * 8 + a], acc);
        acc = fmaf(ev.w, attn_W[(d + 3) * 8 + a], acc);
      }
      stg1(&ep[((size_t)b * TE + t) * 8 + a], acc);
    }
    if (idx < 4 * HH) {
      int bb = idx >> 9, j = idx & 511;
      stg1(&dcat[(size_t)(g * 4 + bb) * DCW + CTXD + j], 0.0f);
    }
  }

  const int lane = tid & 63, w = tid >> 6;
  const int ks = w & 3, rh = w >> 2;
  const int rq = lane >> 4, kl = lane & 15;

  // GRU register weights: rows r = rh*24 + rq*6 + ri (r = gate*16+col)
  // p=0: x chunk c=ks; p=1..4: ctx chunk c=4+4ks+(p-1); p=5,6: h chunk c=20+2ks+(p-5)
  float4 WD[6][7];
  #pragma unroll
  for (int ri = 0; ri < 6; ++ri) {
    int r = rh * 24 + rq * 6 + ri;
    int o = (r >> 4) * HH + cg * 16 + (r & 15);
    WD[ri][0] = *((const float4*)gWih + (size_t)o * 320 + ks * 16 + kl);
    #pragma unroll
    for (int p = 1; p < 5; ++p) {
      int c = 4 + 4 * ks + (p - 1);
      WD[ri][p] = *((const float4*)gWih + (size_t)o * 320 + c * 16 + kl);
    }
    WD[ri][5] = *((const float4*)gWhh + (size_t)o * 128 + (2 * ks) * 16 + kl);
    WD[ri][6] = *((const float4*)gWhh + (size_t)o * 128 + (2 * ks + 1) * 16 + kl);
  }

  // updater (tid<64): (b_u = tid>>4, col_u = tid&15); h-state in register
  const int b_u = tid >> 4, col_u = tid & 15;
  const int j_u = cg * 16 + col_u;
  float bRi = 0, bRh = 0, bZi = 0, bZh = 0, bNi = 0, bNh = 0;
  if (tid < 64) {
    bRi = gbih[j_u];          bRh = gbhh[j_u];
    bZi = gbih[HH + j_u];     bZh = gbhh[HH + j_u];
    bNi = gbih[2 * HH + j_u]; bNh = gbhh[2 * HH + j_u];
  }
  float hreg = 0.0f;

  gbarArrive(bar, cg);
  gbarWait(bar, 32);
  int tgt = 64;

  for (int s = 0; s < TD; ++s) {
    // ---- P2: hpv (wave w -> batch w>>1, a-half w&1) ----
    {
      const int bb = w >> 1, b = g * 4 + bb;
      const float4* h4 = (const float4*)(dcat + ((size_t)s * NB + b) * DCW + CTXD);
      float4 ha = h4[lane * 2], hb = h4[lane * 2 + 1];
      #pragma unroll
      for (int i = 0; i < 4; ++i) {
        const int a = (w & 1) * 4 + i;
        const float* wa = attn_W + (size_t)(CTXD + lane * 8) * 8 + a;
        float acc = 0.0f;
        acc = fmaf(ha.x, wa[0],  acc); acc = fmaf(ha.y, wa[8],  acc);
        acc = fmaf(ha.z, wa[16], acc); acc = fmaf(ha.w, wa[24], acc);
        acc = fmaf(hb.x, wa[32], acc); acc = fmaf(hb.y, wa[40], acc);
        acc = fmaf(hb.z, wa[48], acc); acc = fmaf(hb.w, wa[56], acc);
        acc += __shfl_xor(acc, 1);  acc += __shfl_xor(acc, 2);
        acc += __shfl_xor(acc, 4);  acc += __shfl_xor(acc, 8);
        acc += __shfl_xor(acc, 16); acc += __shfl_xor(acc, 32);
        if (lane == 0) hpv[bb][a] = acc;
      }
    }
    __syncthreads();
    {
      const int bb = tid >> 7, t = tid & 127;
      const int b = g * 4 + bb;
      float evv = -1e9f;
      if (t < lensh[bb]) {
        const float* e8 = &ep[((size_t)b * TE + t) * 8];
        float4 ea = *(const float4*)e8, eb2 = *(const float4*)(e8 + 4);
        evv  = tanhf(ea.x + hpv[bb][0]) * av8v[0];
        evv += tanhf(ea.y + hpv[bb][1]) * av8v[1];
        evv += tanhf(ea.z + hpv[bb][2]) * av8v[2];
        evv += tanhf(ea.w + hpv[bb][3]) * av8v[3];
        evv += tanhf(eb2.x + hpv[bb][4]) * av8v[4];
        evv += tanhf(eb2.y + hpv[bb][5]) * av8v[5];
        evv += tanhf(eb2.z + hpv[bb][6]) * av8v[6];
        evv += tanhf(eb2.w + hpv[bb][7]) * av8v[7];
      }
      elds[bb][t] = evv;
    }
    __syncthreads();
    if (tid < 256) {
      const int bb = tid >> 6, i = tid & 63;
      float m = fmaxf(elds[bb][i], elds[bb][i + 64]);
      m = fmaxf(m, __shfl_xor(m, 1));  m = fmaxf(m, __shfl_xor(m, 2));
      m = fmaxf(m, __shfl_xor(m, 4));  m = fmaxf(m, __shfl_xor(m, 8));
      m = fmaxf(m, __shfl_xor(m, 16)); m = fmaxf(m, __shfl_xor(m, 32));
      if (i == 0) mxs[bb] = m;
    }
    __syncthreads();
    {
      const int bb = tid >> 7, t = tid & 127;
      wlds[bb][t] = expf(elds[bb][t] - mxs[bb]);
    }
    __syncthreads();
    if (tid < 256) {
      const int bb = tid >> 6, i = tid & 63;
      float sm = wlds[bb][i] + wlds[bb][i + 64];
      sm += __shfl_xor(sm, 1);  sm += __shfl_xor(sm, 2);
      sm += __shfl_xor(sm, 4);  sm += __shfl_xor(sm, 8);
      sm += __shfl_xor(sm, 16); sm += __shfl_xor(sm, 32);
      if (i == 0) invs[bb] = 1.0f / sm;
    }
    {
      const int bb = tid >> 7, r2 = tid & 127, tq = r2 >> 5, dq = r2 & 31;
      const int b = g * 4 + bb;
      float acc = 0.0f;
      const float* ebp = eo + ((size_t)b * TE + tq * 32) * CTXD + cg * 32 + dq;
      #pragma unroll 4
      for (int t = 0; t < 32; ++t)
        acc = fmaf(wlds[bb][tq * 32 + t], ebp[(size_t)t * CTXD], acc);
      cpart[bb][tq][dq] = acc;
    }
    __syncthreads();
    if (tid < 128) {
      const int bb = tid >> 5, dq = tid & 31;
      float c = (cpart[bb][0][dq] + cpart[bb][1][dq] +
                 cpart[bb][2][dq] + cpart[bb][3][dq]) * invs[bb];
      stg1(&dcat[((size_t)s * NB + g * 4 + bb) * DCW + cg * 32 + dq], c);
    }
    gbarArrive(bar, cg);

    // ---- shadow: GRU x-dots + h-dots (indep of ctx; h_s cached from hpv) ----
    #pragma unroll
    for (int bb = 0; bb < 4; ++bb) {
      const int b = g * 4 + bb;
      const int tok = tokD[s][bb];
      float4 ux = *((const float4*)emb_tgt + (size_t)tok * 64 + ks * 16 + kl);
      const float4* d4 = (const float4*)dcat + ((size_t)s * NB + b) * (DCW / 4);
      float4 uh0 = d4[(16 + 2 * ks) * 16 + kl];
      float4 uh1 = d4[(17 + 2 * ks) * 16 + kl];
      float si[6], sh[6];
      #pragma unroll
      for (int ri = 0; ri < 6; ++ri) {
        float4 aI = {0, 0, 0, 0}, aH = {0, 0, 0, 0};
        fma4(aI, WD[ri][0], ux);
        fma4(aH, WD[ri][5], uh0);
        fma4(aH, WD[ri][6], uh1);
        si[ri] = hsum4(aI); sh[ri] = hsum4(aH);
      }
      #pragma unroll
      for (int ri = 0; ri < 6; ++ri) {
        si[ri] += __shfl_xor(si[ri], 1); sh[ri] += __shfl_xor(sh[ri], 1);
        si[ri] += __shfl_xor(si[ri], 2); sh[ri] += __shfl_xor(sh[ri], 2);
        si[ri] += __shfl_xor(si[ri], 4); sh[ri] += __shfl_xor(sh[ri], 4);
        si[ri] += __shfl_xor(si[ri], 8); sh[ri] += __shfl_xor(sh[ri], 8);
      }
      if (kl == 0) {
        int r0 = rh * 24 + rq * 6;
        #pragma unroll
        for (int ri = 0; ri < 6; ++ri) {
          lds_pd[0][bb][ks][r0 + ri] = si[ri];
          lds_pd[1][bb][ks][r0 + ri] = sh[ri];
        }
      }
    }
    gbarWait(bar, tgt); tgt += 32;   // ctx ready

    // ---- on-path: ctx-dots (4 chunks) + update ----
    for (int bb = 0; bb < 4; ++bb) {
      const int b = g * 4 + bb;
      const float4* d4 = (const float4*)dcat + ((size_t)s * NB + b) * (DCW / 4);
      float4 uc[4];
      #pragma unroll
      for (int p = 0; p < 4; ++p)
        uc[p] = d4[(4 * ks + p) * 16 + kl];
      float sc[6];
      #pragma unroll
      for (int ri = 0; ri < 6; ++ri) {
        float4 a = {0, 0, 0, 0};
        fma4(a, WD[ri][1], uc[0]);
        fma4(a, WD[ri][2], uc[1]);
        fma4(a, WD[ri][3], uc[2]);
        fma4(a, WD[ri][4], uc[3]);
        sc[ri] = hsum4(a);
      }
      #pragma unroll
      for (int ri = 0; ri < 6; ++ri) {
        sc[ri] += __shfl_xor(sc[ri], 1);
        sc[ri] += __shfl_xor(sc[ri], 2);
        sc[ri] += __shfl_xor(sc[ri], 4);
        sc[ri] += __shfl_xor(sc[ri], 8);
      }
      if (kl == 0) {
        int r0 = rh * 24 + rq * 6;
        #pragma unroll
        for (int ri = 0; ri < 6; ++ri)
          lds_pd[0][bb][ks][r0 + ri] += sc[ri];
      }
    }
    __syncthreads();
    if (tid < 64) {
      float giR = 0, ghR = 0, giZ = 0, ghZ = 0, giN = 0, ghN = 0;
      #pragma unroll
      for (int k2 = 0; k2 < 4; ++k2) {
        giR += lds_pd[0][b_u][k2][col_u];      ghR += lds_pd[1][b_u][k2][col_u];
        giZ += lds_pd[0][b_u][k2][16 + col_u]; ghZ += lds_pd[1][b_u][k2][16 + col_u];
        giN += lds_pd[0][b_u][k2][32 + col_u]; ghN += lds_pd[1][b_u][k2][32 + col_u];
      }
      float r = sigf(giR + bRi + ghR + bRh);
      float z = sigf(giZ + bZi + ghZ + bZh);
      float n = tanhf(giN + bNi + r * (ghN + bNh));
      float hnew = (1.0f - z) * n + z * hreg;
      hreg = hnew;
      stg1(&dcat[((size_t)(s + 1) * NB + g * 4 + b_u) * DCW + CTXD + j_u], hnew);
    }
    gbarArrive(bar, cg);
    gbarWait(bar, tgt); tgt += 32;   // h_{s+1} ready
  }
}

// ---------------- Classifier: [1024,512] @ clf_W^T [512,32000], relu --------
// 128x128 tile, 256 thr, 8x8 acc/thread.
__global__ void __launch_bounds__(256)
clf_kernel(const float* __restrict__ dcat, const float* __restrict__ W,
           const float* __restrict__ bias, float* __restrict__ out)
{
  asm volatile("buffer_inv sc1" ::: "memory");  // stale-clean-line insurance (replays)
  __shared__ __align__(16) float As[16][132];
  __shared__ __align__(16) float Bs[16][132];
  const int tid = threadIdx.x;
  const int tx = tid & 15, ty = tid >> 4;
  const int n0 = blockIdx.x * 128, m0 = blockIdx.y * 128;
  float acc[8][8] = {};
  const int lr = tid >> 1;            // 0..127
  const int lk = (tid & 1) * 8;       // 0 or 8
  const int r  = m0 + lr;             // r = b*TD + t
  const float* arow = dcat + ((size_t)((r & 31) + 1) * NB + (r >> 5)) * DCW + CTXD;
  const float* brow = W + (size_t)(n0 + lr) * HH;

  for (int kc = 0; kc < HH; kc += 16) {
    float4 av0 = *(const float4*)&arow[kc + lk];
    float4 av1 = *(const float4*)&arow[kc + lk + 4];
    float4 bv0 = *(const float4*)&brow[kc + lk];
    float4 bv1 = *(const float4*)&brow[kc + lk + 4];
    __syncthreads();
    As[lk + 0][lr] = av0.x; As[lk + 1][lr] = av0.y;
    As[lk + 2][lr] = av0.z; As[lk + 3][lr] = av0.w;
    As[lk + 4][lr] = av1.x; As[lk + 5][lr] = av1.y;
    As[lk + 6][lr] = av1.z; As[lk + 7][lr] = av1.w;
    Bs[lk + 0][lr] = bv0.x; Bs[lk + 1][lr] = bv0.y;
    Bs[lk + 2][lr] = bv0.z; Bs[lk + 3][lr] = bv0.w;
    Bs[lk + 4][lr] = bv1.x; Bs[lk + 5][lr] = bv1.y;
    Bs[lk + 6][lr] = bv1.z; Bs[lk + 7][lr] = bv1.w;
    __syncthreads();
    #pragma unroll
    for (int kk = 0; kk < 16; ++kk) {
      float a8[8], b8[8];
      *(float4*)&a8[0] = *(const float4*)&As[kk][ty * 8];
      *(float4*)&a8[4] = *(const float4*)&As[kk][ty * 8 + 4];
      *(float4*)&b8[0] = *(const float4*)&Bs[kk][tx * 8];
      *(float4*)&b8[4] = *(const float4*)&Bs[kk][tx * 8 + 4];
      #pragma unroll
      for (int i = 0; i < 8; ++i)
        #pragma unroll
        for (int j = 0; j < 8; ++j)
          acc[i][j] = fmaf(a8[i], b8[j], acc[i][j]);
    }
  }
  const int col = n0 + tx * 8;
  float bb[8];
  *(float4*)&bb[0] = *(const float4*)&bias[col];
  *(float4*)&bb[4] = *(const float4*)&bias[col + 4];
  #pragma unroll
  for (int i = 0; i < 8; ++i) {
    int row = m0 + ty * 8 + i;
    float4 o0, o1;
    o0.x = fmaxf(acc[i][0] + bb[0], 0.0f); o0.y = fmaxf(acc[i][1] + bb[1], 0.0f);
    o0.z = fmaxf(acc[i][2] + bb[2], 0.0f); o0.w = fmaxf(acc[i][3] + bb[3], 0.0f);
    o1.x = fmaxf(acc[i][4] + bb[4], 0.0f); o1.y = fmaxf(acc[i][5] + bb[5], 0.0f);
    o1.z = fmaxf(acc[i][6] + bb[6], 0.0f); o1.w = fmaxf(acc[i][7] + bb[7], 0.0f);
    *(float4*)&out[(size_t)row * VOC + col]     = o0;
    *(float4*)&out[(size_t)row * VOC + col + 4] = o1;
  }
}

extern "C" void kernel_launch(void* const* d_in, const int* in_sizes, int n_in,
                              void* d_out, int out_size, void* d_ws, size_t ws_size,
                              hipStream_t stream)
{
  if (ws_size < (size_t)WSEND * 4) return;  // visible-failure guard

  const int* enc_in  = (const int*)d_in[0];
  const int* enc_len = (const int*)d_in[1];
  const int* dec_in  = (const int*)d_in[2];
  const float* emb_src = (const float*)d_in[4];
  const float* emb_tgt = (const float*)d_in[5];
  const float* Wih_f = (const float*)d_in[6];
  const float* Whh_f = (const float*)d_in[7];
  const float* bih_f = (const float*)d_in[8];
  const float* bhh_f = (const float*)d_in[9];
  const float* Wih_b = (const float*)d_in[10];
  const float* Whh_b = (const float*)d_in[11];
  const float* bih_b = (const float*)d_in[12];
  const float* bhh_b = (const float*)d_in[13];
  const float* gWih  = (const float*)d_in[14];
  const float* gWhh  = (const float*)d_in[15];
  const float* gbih  = (const float*)d_in[16];
  const float* gbhh  = (const float*)d_in[17];
  const float* attn_W = (const float*)d_in[18];
  const float* attn_b = (const float*)d_in[19];
  const float* attn_v = (const float*)d_in[20];
  const float* clf_W = (const float*)d_in[21];
  const float* clf_b = (const float*)d_in[22];
  float* ws  = (float*)d_ws;
  float* out = (float*)d_out;

  hipMemsetAsync(d_ws, 0, 8192, stream);  // barrier lines (16 groups)
  scan_kernel<<<256, 512, 0, stream>>>(enc_in, enc_len, emb_src,
      Wih_f, Whh_f, bih_f, bhh_f, Wih_b, Whh_b, bih_b, bhh_b, ws);
  dec_kernel<<<256, 512, 0, stream>>>(dec_in, enc_len, emb_tgt,
      gWih, gWhh, gbih, gbhh, attn_W, attn_b, attn_v, ws);
  dim3 cg(VOC / 128, (NB * TD) / 128);
  clf_kernel<<<cg, 256, 0, stream>>>(ws + ODC, clf_W, clf_b, out);
}